// Round 7
// baseline (1196.554 us; speedup 1.0000x reference)
//
#include <hip/hip_runtime.h>
#include <hip/hip_bf16.h>
#include <math.h>

#define DIM 7168
#define NE 256
#define NG 8
#define GSZ 32
#define TOPG 4
#define TOPK_N 8

typedef short bf16x8 __attribute__((ext_vector_type(8)));
typedef float f32x4 __attribute__((ext_vector_type(4)));

#define DREL 2.2e-4   // covers |p_true - p_tilde| <= DREL * p_tilde (eps_z = 1e-4)

// swizzle: 16B slot kb within a 64B row, spread by row
#define SW(mrow, kb) (((kb) ^ (((mrow) >> 1) & 3)) << 4)

// ---------------- K0: split w into bf16 hi/lo ----------------
__global__ void k0_split_w(const float* __restrict__ w,
                           unsigned short* __restrict__ wsh,
                           unsigned short* __restrict__ wsl) {
    int i = (blockIdx.x * 256 + threadIdx.x) * 4;
    if (i >= NE * DIM) return;
    float4 f = *(const float4*)&w[i];
    ushort4 h, l;
    const float* fp = (const float*)&f;
    unsigned short* hp = (unsigned short*)&h;
    unsigned short* lp = (unsigned short*)&l;
#pragma unroll
    for (int q = 0; q < 4; ++q) {
        float fv = fp[q];
        __hip_bfloat16 hb = __float2bfloat16(fv);
        float hf = __bfloat162float(hb);
        __hip_bfloat16 lb = __float2bfloat16(fv - hf);
        hp[q] = *(unsigned short*)&hb;
        lp[q] = *(unsigned short*)&lb;
    }
    *(ushort4*)&wsh[i] = h;
    *(ushort4*)&wsl[i] = l;
}

// ---------------- K1: split-bf16 MFMA scores + margin routing ----------------
// BM=16 rows/block, all 256 experts; 512 threads (8 waves); grid n/16
#define K1_BM 16
#define K1_BK 32
#define K1_NCH (DIM / K1_BK)   // 224
// LDS bytes: XH[16][32]bf16=1024, XL=1024, WH[256][32]bf16=16384, WL=16384
#define L_XH 0
#define L_XL 1024
#define L_WH 2048
#define L_WL 18432
#define L_TOT 34816

__global__ __launch_bounds__(512) void k1_scores(
    const float* __restrict__ x,
    const unsigned short* __restrict__ wsh, const unsigned short* __restrict__ wsl,
    const float* __restrict__ bias, float* __restrict__ out,
    unsigned* __restrict__ counter, int* __restrict__ list, int n)
{
    __shared__ __align__(16) char sm[L_TOT];
    float (*scf)[NE] = (float(*)[NE])sm;   // overlay after GEMM: [16][256] f32

    const int t    = threadIdx.x;
    const int row0 = blockIdx.x * K1_BM;

    // staging assignment: w: thread t -> expert e=t>>1, k-half kh=t&1 (16 bf16 each arr)
    const int  se = t >> 1;
    const int  kh = t & 1;
    const size_t wgoff = (size_t)se * DIM + kh * 16;
    // x: t<128: row rx=t>>3, k-quad (t&7)*4
    const int  rx = t >> 3;
    const int  qx = t & 7;
    int rxr = row0 + rx; if (rxr > n - 1) rxr = n - 1;
    const size_t xgoff = (size_t)rxr * DIM + qx * 4;

    // compute assignment: wave wv -> experts 32wv..32wv+31 (2 n-frags), all 16 rows
    const int wv = t >> 6;
    const int l  = t & 63;
    const int m  = l & 15;
    const int kb = l >> 4;
    const int aoff  = m * 64 + SW(m, kb);
    const int boff0 = (32 * wv + m) * 64 + SW(m, kb);
    const int boff1 = (32 * wv + 16 + m) * 64 + SW(m, kb);

    f32x4 acc0 = {0.f, 0.f, 0.f, 0.f};
    f32x4 acc1 = {0.f, 0.f, 0.f, 0.f};

    // prefetch chunk 0
    uint4 pwh0 = *(const uint4*)(wsh + wgoff);
    uint4 pwh1 = *(const uint4*)(wsh + wgoff + 8);
    uint4 pwl0 = *(const uint4*)(wsl + wgoff);
    uint4 pwl1 = *(const uint4*)(wsl + wgoff + 8);
    float4 pxv = make_float4(0.f, 0.f, 0.f, 0.f);
    if (t < 128) pxv = *(const float4*)&x[xgoff];

    for (int c = 0; c < K1_NCH; ++c) {
        __syncthreads();   // previous compute done
        // ---- stage chunk c ----
        {
            // w: two 16B slots per array; slot kb0=2*kh, kb1=2*kh+1
            const int b0 = se * 64 + SW(se, 2 * kh);
            const int b1 = se * 64 + SW(se, 2 * kh + 1);
            *(uint4*)(sm + L_WH + b0) = pwh0;
            *(uint4*)(sm + L_WH + b1) = pwh1;
            *(uint4*)(sm + L_WL + b0) = pwl0;
            *(uint4*)(sm + L_WL + b1) = pwl1;
            if (t < 128) {
                const float* fx = (const float*)&pxv;
                short hq[4], lq[4];
#pragma unroll
                for (int q = 0; q < 4; ++q) {
                    float fv = fx[q];
                    __hip_bfloat16 hb = __float2bfloat16(fv);
                    float hf = __bfloat162float(hb);
                    __hip_bfloat16 lb = __float2bfloat16(fv - hf);
                    hq[q] = *(short*)&hb;
                    lq[q] = *(short*)&lb;
                }
                const int xb = rx * 64 + SW(rx, qx >> 1) + (qx & 1) * 8;
                *(short4*)(sm + L_XH + xb) = make_short4(hq[0], hq[1], hq[2], hq[3]);
                *(short4*)(sm + L_XL + xb) = make_short4(lq[0], lq[1], lq[2], lq[3]);
            }
        }
        // ---- prefetch chunk c+1 ----
        {
            const int cn = (c + 1 < K1_NCH) ? c + 1 : c;
            const size_t k0 = (size_t)cn * K1_BK;
            pwh0 = *(const uint4*)(wsh + wgoff + k0);
            pwh1 = *(const uint4*)(wsh + wgoff + k0 + 8);
            pwl0 = *(const uint4*)(wsl + wgoff + k0);
            pwl1 = *(const uint4*)(wsl + wgoff + k0 + 8);
            if (t < 128) pxv = *(const float4*)&x[xgoff + k0];
        }
        __syncthreads();   // staging visible
        // ---- compute: 3-term split MFMA ----
        bf16x8 a_h = *(const bf16x8*)(sm + L_XH + aoff);
        bf16x8 a_l = *(const bf16x8*)(sm + L_XL + aoff);
        bf16x8 b_h0 = *(const bf16x8*)(sm + L_WH + boff0);
        bf16x8 b_l0 = *(const bf16x8*)(sm + L_WL + boff0);
        bf16x8 b_h1 = *(const bf16x8*)(sm + L_WH + boff1);
        bf16x8 b_l1 = *(const bf16x8*)(sm + L_WL + boff1);
        acc0 = __builtin_amdgcn_mfma_f32_16x16x32_bf16(a_h, b_h0, acc0, 0, 0, 0);
        acc0 = __builtin_amdgcn_mfma_f32_16x16x32_bf16(a_h, b_l0, acc0, 0, 0, 0);
        acc0 = __builtin_amdgcn_mfma_f32_16x16x32_bf16(a_l, b_h0, acc0, 0, 0, 0);
        acc1 = __builtin_amdgcn_mfma_f32_16x16x32_bf16(a_h, b_h1, acc1, 0, 0, 0);
        acc1 = __builtin_amdgcn_mfma_f32_16x16x32_bf16(a_h, b_l1, acc1, 0, 0, 0);
        acc1 = __builtin_amdgcn_mfma_f32_16x16x32_bf16(a_l, b_h1, acc1, 0, 0, 0);
    }

    __syncthreads();   // done reading staging; overlay scf
    // D layout (verified family): col = lane&15, row = 4*(lane>>4)+j
#pragma unroll
    for (int j = 0; j < 4; ++j) {
        scf[4 * kb + j][32 * wv + m]      = acc0[j];
        scf[4 * kb + j][32 * wv + 16 + m] = acc1[j];
    }
    __syncthreads();

    // ---- routing with margin certificates (threads 0..15) ----
    if (t < K1_BM) {
        const int row = row0 + t;
        if (row < n) {
            float* srow = scf[t];
            double zmax = -1e300;
            for (int e = 0; e < NE; ++e) zmax = fmax(zmax, (double)srow[e]);
            double Z = 0.0;
            for (int e = 0; e < NE; ++e) {
                double p = exp((double)srow[e] - zmax);
                srow[e] = (float)p;
                Z += p;
            }
            const double invZ = 1.0 / Z;

            bool flag = false;
            double gs[NG], dg[NG];
            for (int g = 0; g < NG; ++g) {
                double v1 = -1e300, v2 = -1e300, v3 = -1e300;
                double d1 = 0, d2 = 0, d3 = 0;
                for (int i = 0; i < GSZ; ++i) {
                    double p = (double)srow[g * GSZ + i] * invZ;
                    double v = p + (double)bias[g * GSZ + i];
                    double d = DREL * p;
                    if (v > v1)      { v3 = v2; d3 = d2; v2 = v1; d2 = d1; v1 = v; d1 = d; }
                    else if (v > v2) { v3 = v2; d3 = d2; v2 = v;  d2 = d; }
                    else if (v > v3) { v3 = v;  d3 = d; }
                }
                if (v2 - v3 <= d2 + d3) flag = true;   // top-2 membership uncertain
                gs[g] = v1 + v2; dg[g] = d1 + d2;
            }
            unsigned keep = 0;
            for (int tt = 0; tt < TOPG; ++tt) {
                double best = -1e300; int bg = 0;
                for (int g = 0; g < NG; ++g)
                    if (!((keep >> g) & 1u) && gs[g] > best) { best = gs[g]; bg = g; }
                keep |= 1u << bg;
            }
            {
                double mn = 1e300, mx = -1e300;
                for (int g = 0; g < NG; ++g) {
                    if ((keep >> g) & 1u) mn = fmin(mn, gs[g] - dg[g]);
                    else                  mx = fmax(mx, gs[g] + dg[g]);
                }
                if (mn <= mx) flag = true;             // group set uncertain
            }
            unsigned long long tk[4] = {0ull, 0ull, 0ull, 0ull};
            double pv[9], pd[9]; int pe[9];
            for (int pp = 0; pp < 9; ++pp) {
                double best = -1e300, bd = 0; int be = 0;
                for (int e = 0; e < NE; ++e) {
                    if (!((keep >> (e >> 5)) & 1u)) continue;
                    if ((tk[e >> 6] >> (e & 63)) & 1ull) continue;
                    double p = (double)srow[e] * invZ;
                    double s = p + (double)bias[e];
                    if (s > best) { best = s; bd = DREL * p; be = e; }
                }
                tk[be >> 6] |= 1ull << (be & 63);
                pv[pp] = best; pd[pp] = bd; pe[pp] = be;
            }
            for (int i = 0; i < 8; ++i)
                if (pv[i] - pv[i + 1] <= pd[i] + pd[i + 1]) flag = true;  // order uncertain

            float* out_w = out;
            float* out_i = out + (size_t)n * TOPK_N;
            for (int pp = 0; pp < TOPK_N; ++pp) {
                out_w[(size_t)row * TOPK_N + pp] = (float)((double)srow[pe[pp]] * invZ * 2.5);
                out_i[(size_t)row * TOPK_N + pp] = (float)pe[pp];
            }
            if (flag) {
                unsigned idx = atomicAdd(counter, 1u);
                if (idx < 8192u) list[idx] = row;
            }
        }
    }
}

// ---------------- K2: exact fp64 recompute for flagged rows ----------------
#define K2_ROWS 4
#define K2_CH 512
__global__ __launch_bounds__(1024) void k2_exact(
    const float* __restrict__ x, const float* __restrict__ w,
    const float* __restrict__ bias, float* __restrict__ out,
    const unsigned* __restrict__ counter, const int* __restrict__ list, int n)
{
    __shared__ __align__(16) char sm2[41984];
    double (*xs)[K2_CH + 2]      = (double(*)[K2_CH + 2])sm2;       // [4][514]
    double (*pf)[NE][K2_ROWS]    = (double(*)[NE][K2_ROWS])sm2;     // overlay [4][256][4]
    double (*sc)[NE]             = (double(*)[NE])(sm2 + 32768);    // [4][256]

    const unsigned F = min(*counter, 8192u);
    const int base = blockIdx.x * K2_ROWS;
    if ((unsigned)base >= F) return;
    const int t = threadIdx.x;
    int rows[K2_ROWS];
#pragma unroll
    for (int i = 0; i < K2_ROWS; ++i)
        rows[i] = ((unsigned)(base + i) < F) ? list[base + i] : list[base];

    const int e  = t & 255;
    const int sl = t >> 8;
    double a0 = 0, a1 = 0, a2 = 0, a3 = 0;
    for (int c = 0; c < DIM / K2_CH; ++c) {
        __syncthreads();
        if (t < 512) {
            int r  = t >> 7;
            int k4 = (t & 127) * 4;
            float4 v = *(const float4*)&x[(size_t)rows[r] * DIM + c * K2_CH + k4];
            xs[r][k4 + 0] = (double)v.x; xs[r][k4 + 1] = (double)v.y;
            xs[r][k4 + 2] = (double)v.z; xs[r][k4 + 3] = (double)v.w;
        }
        __syncthreads();
        const float* wp = &w[(size_t)e * DIM + c * K2_CH + sl * 128];
        const int klb = sl * 128;
        for (int k4 = 0; k4 < 128; k4 += 4) {
            float4 wf = *(const float4*)&wp[k4];
            const float* wfp = (const float*)&wf;
#pragma unroll
            for (int q = 0; q < 4; ++q) {
                double wv = (double)wfp[q];
                int kl = klb + k4 + q;
                a0 = fma(xs[0][kl], wv, a0);
                a1 = fma(xs[1][kl], wv, a1);
                a2 = fma(xs[2][kl], wv, a2);
                a3 = fma(xs[3][kl], wv, a3);
            }
        }
    }
    __syncthreads();
    pf[sl][e][0] = a0; pf[sl][e][1] = a1; pf[sl][e][2] = a2; pf[sl][e][3] = a3;
    __syncthreads();
    {
        int r = t >> 8, ee = t & 255;
        sc[r][ee] = ((pf[0][ee][r] + pf[1][ee][r]) + pf[2][ee][r]) + pf[3][ee][r];
    }
    __syncthreads();

    if (t < K2_ROWS && (unsigned)(base + t) < F) {
        const int row = rows[t];
        double* srow = sc[t];
        double zmax = -1e300;
        for (int ee = 0; ee < NE; ++ee) zmax = fmax(zmax, srow[ee]);
        double Z = 0.0;
        for (int ee = 0; ee < NE; ++ee) {
            double p = exp(srow[ee] - zmax);
            srow[ee] = p;
            Z += p;
        }
        const double invZ = 1.0 / Z;
        double gs[NG];
        for (int g = 0; g < NG; ++g) {
            double m1 = -1e300, m2 = -1e300;
            for (int i = 0; i < GSZ; ++i) {
                double v = srow[g * GSZ + i] * invZ + (double)bias[g * GSZ + i];
                if (v > m1) { m2 = m1; m1 = v; }
                else if (v > m2) { m2 = v; }
            }
            gs[g] = m1 + m2;
        }
        unsigned keep = 0;
        for (int tt = 0; tt < TOPG; ++tt) {
            double best = -1e300; int bg = 0;
            for (int g = 0; g < NG; ++g)
                if (!((keep >> g) & 1u) && gs[g] > best) { best = gs[g]; bg = g; }
            keep |= 1u << bg;
        }
        unsigned long long tk[4] = {0ull, 0ull, 0ull, 0ull};
        float* out_w = out;
        float* out_i = out + (size_t)n * TOPK_N;
        for (int pp = 0; pp < TOPK_N; ++pp) {
            double best = -1e300; int be = 0;
            for (int ee = 0; ee < NE; ++ee) {
                if (!((keep >> (ee >> 5)) & 1u)) continue;
                if ((tk[ee >> 6] >> (ee & 63)) & 1ull) continue;
                double s = srow[ee] * invZ + (double)bias[ee];
                if (s > best) { best = s; be = ee; }
            }
            tk[be >> 6] |= 1ull << (be & 63);
            out_w[(size_t)row * TOPK_N + pp] = (float)(srow[be] * invZ * 2.5);
            out_i[(size_t)row * TOPK_N + pp] = (float)be;
        }
    }
}

// ---------------- fallback (proven r6 fp64 kernel) if ws too small ----------------
#define OBM 32
#define OBK 16
#define ONCH (DIM / OBK)
__global__ __launch_bounds__(512) void gate_kernel_old(
    const float* __restrict__ x, const float* __restrict__ w,
    const float* __restrict__ bias, float* __restrict__ out, int n)
{
    __shared__ __align__(16) char smem[65536];
    float  (*w2)[OBK][NE] = reinterpret_cast<float(*)[OBK][NE]>(smem);
    double (*x2)[OBK][34] = reinterpret_cast<double(*)[OBK][34]>(smem + 32768);
    double (*sc)[OBM]     = reinterpret_cast<double(*)[OBM]>(smem);
    const int t = threadIdx.x;
    const int row0 = blockIdx.x * OBM;
    const int we = t & 255;
    const int h8 = (t >> 8) * 8;
    const size_t wbase = (size_t)we * DIM + h8;
    const int rx = t >> 2;
    const int kx = (t & 3) * 4;
    int rr = row0 + rx; if (rr > n - 1) rr = n - 1;
    const size_t xbase = (size_t)rr * DIM + kx;
    const int wv = t >> 6, lane = t & 63;
    const int h = wv & 1, rg = wv >> 1, rb = 8 * rg;
    const int e0 = 128 * h + 2 * lane;
    double acc[8][2];
#pragma unroll
    for (int i = 0; i < 8; ++i) { acc[i][0] = 0.0; acc[i][1] = 0.0; }
    float4 wra = *(const float4*)&w[wbase];
    float4 wrb = *(const float4*)&w[wbase + 4];
    float4 xr = make_float4(0.f, 0.f, 0.f, 0.f);
    if (t < 128) xr = *(const float4*)&x[xbase];
    for (int c = 0; c < ONCH; ++c) {
        const int b = c & 1;
        const float* fa = (const float*)&wra;
        const float* fb = (const float*)&wrb;
#pragma unroll
        for (int q = 0; q < 4; ++q) {
            w2[b][h8 + q][we] = fa[q];
            w2[b][h8 + 4 + q][we] = fb[q];
        }
        if (t < 128) {
            const float* fx = (const float*)&xr;
#pragma unroll
            for (int q = 0; q < 4; ++q) x2[b][kx + q][rx] = (double)fx[q];
        }
        const size_t k0 = (size_t)((c + 1 < ONCH) ? c + 1 : c) * OBK;
        wra = *(const float4*)&w[wbase + k0];
        wrb = *(const float4*)&w[wbase + k0 + 4];
        if (t < 128) xr = *(const float4*)&x[xbase + k0];
        __syncthreads();
#pragma unroll
        for (int kk = 0; kk < OBK; ++kk) {
            const float2 wf = *(const float2*)&w2[b][kk][e0];
            const double wd0 = (double)wf.x, wd1 = (double)wf.y;
            const double2 xp0 = *(const double2*)&x2[b][kk][rb];
            const double2 xp1 = *(const double2*)&x2[b][kk][rb + 2];
            const double2 xp2 = *(const double2*)&x2[b][kk][rb + 4];
            const double2 xp3 = *(const double2*)&x2[b][kk][rb + 6];
            const double xv[8] = {xp0.x, xp0.y, xp1.x, xp1.y, xp2.x, xp2.y, xp3.x, xp3.y};
#pragma unroll
            for (int i = 0; i < 8; ++i) {
                acc[i][0] = fma(xv[i], wd0, acc[i][0]);
                acc[i][1] = fma(xv[i], wd1, acc[i][1]);
            }
        }
    }
    __syncthreads();
#pragma unroll
    for (int j = 0; j < 2; ++j)
#pragma unroll
        for (int q = 0; q < 4; ++q) {
            double2 v; v.x = acc[2 * q][j]; v.y = acc[2 * q + 1][j];
            *(double2*)&sc[e0 + j][rb + 2 * q] = v;
        }
    __syncthreads();
    if (t < OBM) {
        const int row = row0 + t;
        if (row < n) {
            double zmax = -1e300;
            for (int e = 0; e < NE; ++e) zmax = fmax(zmax, sc[e][t]);
            double Z = 0.0;
            for (int e = 0; e < NE; ++e) { double p = exp(sc[e][t] - zmax); sc[e][t] = p; Z += p; }
            const double invZ = 1.0 / Z;
            double gs[NG];
            for (int g = 0; g < NG; ++g) {
                double m1 = -1e300, m2 = -1e300;
                for (int i = 0; i < GSZ; ++i) {
                    double v = sc[g * GSZ + i][t] * invZ + (double)bias[g * GSZ + i];
                    if (v > m1) { m2 = m1; m1 = v; } else if (v > m2) m2 = v;
                }
                gs[g] = m1 + m2;
            }
            unsigned keep = 0;
            for (int tt = 0; tt < TOPG; ++tt) {
                double best = -1e300; int bg = 0;
                for (int g = 0; g < NG; ++g)
                    if (!((keep >> g) & 1u) && gs[g] > best) { best = gs[g]; bg = g; }
                keep |= 1u << bg;
            }
            unsigned long long tk[4] = {0ull, 0ull, 0ull, 0ull};
            float* out_w = out;
            float* out_i = out + (size_t)n * TOPK_N;
            for (int pp = 0; pp < TOPK_N; ++pp) {
                double best = -1e300; int be = 0;
                for (int e = 0; e < NE; ++e) {
                    if (!((keep >> (e >> 5)) & 1u)) continue;
                    if ((tk[e >> 6] >> (e & 63)) & 1ull) continue;
                    double s = sc[e][t] * invZ + (double)bias[e];
                    if (s > best) { best = s; be = e; }
                }
                tk[be >> 6] |= 1ull << (be & 63);
                out_w[(size_t)row * TOPK_N + pp] = (float)(sc[be][t] * invZ * 2.5);
                out_i[(size_t)row * TOPK_N + pp] = (float)be;
            }
        }
    }
}

extern "C" void kernel_launch(void* const* d_in, const int* in_sizes, int n_in,
                              void* d_out, int out_size, void* d_ws, size_t ws_size,
                              hipStream_t stream) {
    const float* x  = (const float*)d_in[0];
    const float* w  = (const float*)d_in[1];
    const float* b  = (const float*)d_in[2];
    float* out      = (float*)d_out;
    const int n     = in_sizes[0] / DIM;

    const size_t need = 65536 + 2 * (size_t)NE * DIM * sizeof(unsigned short) + 4096;
    if (ws_size < need) {
        gate_kernel_old<<<(n + OBM - 1) / OBM, 512, 0, stream>>>(x, w, b, out, n);
        return;
    }
    char* ws = (char*)d_ws;
    unsigned* counter   = (unsigned*)ws;
    int* list           = (int*)(ws + 64);
    unsigned short* wsh = (unsigned short*)(ws + 65536);
    unsigned short* wsl = wsh + (size_t)NE * DIM;

    hipMemsetAsync(counter, 0, 4, stream);
    k0_split_w<<<(NE * DIM / 4 + 255) / 256, 256, 0, stream>>>(w, wsh, wsl);
    k1_scores<<<(n + K1_BM - 1) / K1_BM, 512, 0, stream>>>(x, wsh, wsl, b, out, counter, list, n);
    k2_exact<<<(n + K2_ROWS - 1) / K2_ROWS, 1024, 0, stream>>>(x, w, b, out, counter, list, n);
}

// Round 8
// 1052.336 us; speedup vs baseline: 1.1370x; 1.1370x over previous
//
#include <hip/hip_runtime.h>
#include <math.h>

#define DIM 7168
#define NE 256
#define NG 8
#define GSZ 32
#define TOPG 4
#define TOPK_N 8
#define NKT 224          // DIM/32 k-tiles total
#define KSPLIT 8
#define KTS 28           // NKT/KSPLIT
#define KSLICE 896       // DIM/KSPLIT
#define BM 128

typedef short bf16x8 __attribute__((ext_vector_type(8)));
typedef float f32x4 __attribute__((ext_vector_type(4)));

#define DREL 2.2e-4

__device__ __forceinline__ unsigned short bf16_rne(float f) {
    unsigned u = __float_as_uint(f);
    unsigned r = u + 0x7FFFu + ((u >> 16) & 1u);
    return (unsigned short)(r >> 16);
}
__device__ __forceinline__ float bf16_to_f32(unsigned short h) {
    return __uint_as_float(((unsigned)h) << 16);
}

// ---------------- K0: repack W into fragment-major bf16 hi/lo ----------------
// frag id gid = (ct*NKT + t)*64 + l ; element j: w[ct*16+(l&15)][t*32+(l>>4)*8+j]
__global__ void k0_repack(const float* __restrict__ w,
                          unsigned short* __restrict__ wh,
                          unsigned short* __restrict__ wl) {
    const int gid = blockIdx.x * 256 + threadIdx.x;
    if (gid >= 16 * NKT * 64) return;
    const int l  = gid & 63;
    const int t  = (gid >> 6) % NKT;
    const int ct = gid / (NKT * 64);
    const int e  = ct * 16 + (l & 15);
    const int k0 = t * 32 + (l >> 4) * 8;
    const float* src = w + (size_t)e * DIM + k0;
    float4 u0 = *(const float4*)src;
    float4 u1 = *(const float4*)(src + 4);
    const float uu[8] = {u0.x, u0.y, u0.z, u0.w, u1.x, u1.y, u1.z, u1.w};
    ushort4 ho[2], lo[2];
    unsigned short* hp = (unsigned short*)ho;
    unsigned short* lp = (unsigned short*)lo;
#pragma unroll
    for (int q = 0; q < 8; ++q) {
        unsigned short hb = bf16_rne(uu[q]);
        float hf = bf16_to_f32(hb);
        unsigned short lb = bf16_rne(uu[q] - hf);
        hp[q] = hb; lp[q] = lb;
    }
    *(ushort4*)(wh + (size_t)gid * 8)     = ho[0];
    *(ushort4*)(wh + (size_t)gid * 8 + 4) = ho[1];
    *(ushort4*)(wl + (size_t)gid * 8)     = lo[0];
    *(ushort4*)(wl + (size_t)gid * 8 + 4) = lo[1];
}

// ---------------- K1: fragment-direct 3-term split-bf16 GEMM ----------------
// grid = (np/BM)*KSPLIT blocks; ks = blockIdx&7 (XCD-pinned W slice), rb = blockIdx>>3
// 512 thr, 8 waves; wave: rt pair = 2*(w&3), ct half = 8*(w>>2); no LDS, no barriers
__global__ __launch_bounds__(512, 2) void k1_gemm(
    const float* __restrict__ x,
    const unsigned short* __restrict__ wh, const unsigned short* __restrict__ wl,
    float* __restrict__ part, int n, int np)
{
    const int t  = threadIdx.x;
    const int l  = t & 63;
    const int wv = t >> 6;
    const int ks = blockIdx.x & 7;
    const int rb = blockIdx.x >> 3;
    const int rtb = 2 * (wv & 3);
    const int ctb = 8 * (wv >> 2);
    const int mrow  = l & 15;
    const int kslot = l >> 4;

    f32x4 acc[2][8];
#pragma unroll
    for (int rr = 0; rr < 2; ++rr)
#pragma unroll
        for (int ci = 0; ci < 8; ++ci) acc[rr][ci] = (f32x4){0.f, 0.f, 0.f, 0.f};

    size_t xoff[2];
#pragma unroll
    for (int rr = 0; rr < 2; ++rr) {
        int row = rb * BM + (rtb + rr) * 16 + mrow;
        if (row > n - 1) row = n - 1;
        xoff[rr] = (size_t)row * DIM + ks * KSLICE + kslot * 8;
    }
    size_t boff[8];
#pragma unroll
    for (int ci = 0; ci < 8; ++ci)
        boff[ci] = ((size_t)((ctb + ci) * NKT + ks * KTS) * 64 + l) * 8;

#pragma unroll 1
    for (int tt = 0; tt < KTS; ++tt) {
        bf16x8 ah[2], al[2];
#pragma unroll
        for (int rr = 0; rr < 2; ++rr) {
            const float* xp = x + xoff[rr] + (size_t)tt * 32;
            float4 u0 = *(const float4*)xp;
            float4 u1 = *(const float4*)(xp + 4);
            const float uu[8] = {u0.x, u0.y, u0.z, u0.w, u1.x, u1.y, u1.z, u1.w};
            bf16x8 hh, ll;
#pragma unroll
            for (int q = 0; q < 8; ++q) {
                unsigned short hb = bf16_rne(uu[q]);
                float hf = bf16_to_f32(hb);
                unsigned short lb = bf16_rne(uu[q] - hf);
                hh[q] = (short)hb; ll[q] = (short)lb;
            }
            ah[rr] = hh; al[rr] = ll;
        }
        bf16x8 bh[8], bl[8];
#pragma unroll
        for (int ci = 0; ci < 8; ++ci) {
            bh[ci] = *(const bf16x8*)(wh + boff[ci] + (size_t)tt * 512);
            bl[ci] = *(const bf16x8*)(wl + boff[ci] + (size_t)tt * 512);
        }
#pragma unroll
        for (int ci = 0; ci < 8; ++ci)
#pragma unroll
            for (int rr = 0; rr < 2; ++rr) {
                acc[rr][ci] = __builtin_amdgcn_mfma_f32_16x16x32_bf16(ah[rr], bh[ci], acc[rr][ci], 0, 0, 0);
                acc[rr][ci] = __builtin_amdgcn_mfma_f32_16x16x32_bf16(ah[rr], bl[ci], acc[rr][ci], 0, 0, 0);
                acc[rr][ci] = __builtin_amdgcn_mfma_f32_16x16x32_bf16(al[rr], bh[ci], acc[rr][ci], 0, 0, 0);
            }
    }

    float* pb = part + (size_t)ks * np * NE;
#pragma unroll
    for (int rr = 0; rr < 2; ++rr)
#pragma unroll
        for (int ci = 0; ci < 8; ++ci) {
            const int rl = rb * BM + (rtb + rr) * 16 + 4 * kslot;
            const int e  = (ctb + ci) * 16 + mrow;
#pragma unroll
            for (int j = 0; j < 4; ++j)
                pb[(size_t)(rl + j) * NE + e] = acc[rr][ci][j];
        }
}

// ---------------- K1b: combine partials + certificate routing ----------------
__global__ __launch_bounds__(256) void k1b_route(
    const float* __restrict__ part, const float* __restrict__ bias,
    float* __restrict__ out, unsigned* __restrict__ counter,
    int* __restrict__ list, int n, int np, unsigned lcap)
{
    __shared__ float sc[32][NE + 2];
    const int t  = threadIdx.x;
    const int r0 = blockIdx.x * 32;
#pragma unroll 1
    for (int r = 0; r < 32; ++r) {
        const size_t off = (size_t)(r0 + r) * NE + t;
        float z = 0.f;
#pragma unroll
        for (int ks = 0; ks < KSPLIT; ++ks)
            z += part[(size_t)ks * np * NE + off];
        sc[r][t] = z;
    }
    __syncthreads();

    if (t < 32) {
        const int row = r0 + t;
        if (row < n) {
            float* srow = sc[t];
            float zmaxf = -3e38f;
            for (int e = 0; e < NE; ++e) zmaxf = fmaxf(zmaxf, srow[e]);
            double Z = 0.0;
            for (int e = 0; e < NE; ++e) {
                float p = __expf(srow[e] - zmaxf);
                srow[e] = p;
                Z += (double)p;
            }
            const double invZ = 1.0 / Z;

            bool flag = false;
            double gs[NG], dg[NG];
            for (int g = 0; g < NG; ++g) {
                double v1 = -1e300, v2 = -1e300, v3 = -1e300;
                double d1 = 0, d2 = 0, d3 = 0;
                for (int i = 0; i < GSZ; ++i) {
                    double p = (double)srow[g * GSZ + i] * invZ;
                    double v = p + (double)bias[g * GSZ + i];
                    double d = DREL * p;
                    if (v > v1)      { v3 = v2; d3 = d2; v2 = v1; d2 = d1; v1 = v; d1 = d; }
                    else if (v > v2) { v3 = v2; d3 = d2; v2 = v;  d2 = d; }
                    else if (v > v3) { v3 = v;  d3 = d; }
                }
                if (v2 - v3 <= d2 + d3) flag = true;
                gs[g] = v1 + v2; dg[g] = d1 + d2;
            }
            unsigned keep = 0;
            for (int tt = 0; tt < TOPG; ++tt) {
                double best = -1e300; int bg = 0;
                for (int g = 0; g < NG; ++g)
                    if (!((keep >> g) & 1u) && gs[g] > best) { best = gs[g]; bg = g; }
                keep |= 1u << bg;
            }
            {
                double mn = 1e300, mx = -1e300;
                for (int g = 0; g < NG; ++g) {
                    if ((keep >> g) & 1u) mn = fmin(mn, gs[g] - dg[g]);
                    else                  mx = fmax(mx, gs[g] + dg[g]);
                }
                if (mn <= mx) flag = true;
            }
            unsigned long long tk[4] = {0ull, 0ull, 0ull, 0ull};
            double pv[9], pd[9]; int pe[9];
            for (int pp = 0; pp < 9; ++pp) {
                double best = -1e300, bd = 0; int be = 0;
                for (int e = 0; e < NE; ++e) {
                    if (!((keep >> (e >> 5)) & 1u)) continue;
                    if ((tk[e >> 6] >> (e & 63)) & 1ull) continue;
                    double p = (double)srow[e] * invZ;
                    double s = p + (double)bias[e];
                    if (s > best) { best = s; bd = DREL * p; be = e; }
                }
                tk[be >> 6] |= 1ull << (be & 63);
                pv[pp] = best; pd[pp] = bd; pe[pp] = be;
            }
            for (int i = 0; i < 8; ++i)
                if (pv[i] - pv[i + 1] <= pd[i] + pd[i + 1]) flag = true;

            float* out_w = out;
            float* out_i = out + (size_t)n * TOPK_N;
            for (int pp = 0; pp < TOPK_N; ++pp) {
                out_w[(size_t)row * TOPK_N + pp] = (float)((double)srow[pe[pp]] * invZ * 2.5);
                out_i[(size_t)row * TOPK_N + pp] = (float)pe[pp];
            }
            if (flag) {
                unsigned idx = atomicAdd(counter, 1u);
                if (idx < lcap) list[idx] = row;
            }
        }
    }
}

// ---------------- K2: exact fp64 recompute for flagged rows ----------------
#define K2_ROWS 4
#define K2_CH 512
__global__ __launch_bounds__(1024) void k2_exact(
    const float* __restrict__ x, const float* __restrict__ w,
    const float* __restrict__ bias, float* __restrict__ out,
    const unsigned* __restrict__ counter, const int* __restrict__ list,
    int n, unsigned lcap)
{
    __shared__ __align__(16) char sm2[41984];
    double (*xs)[K2_CH + 2]   = (double(*)[K2_CH + 2])sm2;
    double (*pf)[NE][K2_ROWS] = (double(*)[NE][K2_ROWS])sm2;
    double (*sc)[NE]          = (double(*)[NE])(sm2 + 32768);

    const unsigned F = min(*counter, lcap);
    const int base = blockIdx.x * K2_ROWS;
    if ((unsigned)base >= F) return;
    const int t = threadIdx.x;
    int rows[K2_ROWS];
#pragma unroll
    for (int i = 0; i < K2_ROWS; ++i)
        rows[i] = ((unsigned)(base + i) < F) ? list[base + i] : list[base];

    const int e  = t & 255;
    const int sl = t >> 8;
    double a0 = 0, a1 = 0, a2 = 0, a3 = 0;
    for (int c = 0; c < DIM / K2_CH; ++c) {
        __syncthreads();
        if (t < 512) {
            int r  = t >> 7;
            int k4 = (t & 127) * 4;
            float4 v = *(const float4*)&x[(size_t)rows[r] * DIM + c * K2_CH + k4];
            xs[r][k4 + 0] = (double)v.x; xs[r][k4 + 1] = (double)v.y;
            xs[r][k4 + 2] = (double)v.z; xs[r][k4 + 3] = (double)v.w;
        }
        __syncthreads();
        const float* wp = &w[(size_t)e * DIM + c * K2_CH + sl * 128];
        const int klb = sl * 128;
        for (int k4 = 0; k4 < 128; k4 += 4) {
            float4 wf = *(const float4*)&wp[k4];
            const float* wfp = (const float*)&wf;
#pragma unroll
            for (int q = 0; q < 4; ++q) {
                double wv = (double)wfp[q];
                int kl = klb + k4 + q;
                a0 = fma(xs[0][kl], wv, a0);
                a1 = fma(xs[1][kl], wv, a1);
                a2 = fma(xs[2][kl], wv, a2);
                a3 = fma(xs[3][kl], wv, a3);
            }
        }
    }
    __syncthreads();
    pf[sl][e][0] = a0; pf[sl][e][1] = a1; pf[sl][e][2] = a2; pf[sl][e][3] = a3;
    __syncthreads();
    {
        int r = t >> 8, ee = t & 255;
        sc[r][ee] = ((pf[0][ee][r] + pf[1][ee][r]) + pf[2][ee][r]) + pf[3][ee][r];
    }
    __syncthreads();

    if (t < K2_ROWS && (unsigned)(base + t) < F) {
        const int row = rows[t];
        double* srow = sc[t];
        double zmax = -1e300;
        for (int ee = 0; ee < NE; ++ee) zmax = fmax(zmax, srow[ee]);
        double Z = 0.0;
        for (int ee = 0; ee < NE; ++ee) {
            double p = exp(srow[ee] - zmax);
            srow[ee] = p;
            Z += p;
        }
        const double invZ = 1.0 / Z;
        double gs[NG];
        for (int g = 0; g < NG; ++g) {
            double m1 = -1e300, m2 = -1e300;
            for (int i = 0; i < GSZ; ++i) {
                double v = srow[g * GSZ + i] * invZ + (double)bias[g * GSZ + i];
                if (v > m1) { m2 = m1; m1 = v; }
                else if (v > m2) { m2 = v; }
            }
            gs[g] = m1 + m2;
        }
        unsigned keep = 0;
        for (int tt = 0; tt < TOPG; ++tt) {
            double best = -1e300; int bg = 0;
            for (int g = 0; g < NG; ++g)
                if (!((keep >> g) & 1u) && gs[g] > best) { best = gs[g]; bg = g; }
            keep |= 1u << bg;
        }
        unsigned long long tk[4] = {0ull, 0ull, 0ull, 0ull};
        float* out_w = out;
        float* out_i = out + (size_t)n * TOPK_N;
        for (int pp = 0; pp < TOPK_N; ++pp) {
            double best = -1e300; int be = 0;
            for (int ee = 0; ee < NE; ++ee) {
                if (!((keep >> (ee >> 5)) & 1u)) continue;
                if ((tk[ee >> 6] >> (ee & 63)) & 1ull) continue;
                double s = srow[ee] * invZ + (double)bias[ee];
                if (s > best) { best = s; be = ee; }
            }
            tk[be >> 6] |= 1ull << (be & 63);
            out_w[(size_t)row * TOPK_N + pp] = (float)(srow[be] * invZ * 2.5);
            out_i[(size_t)row * TOPK_N + pp] = (float)be;
        }
    }
}

// ---------------- fallback (proven r6 fp64 kernel) if ws too small ----------------
#define OBM 32
#define OBK 16
#define ONCH (DIM / OBK)
__global__ __launch_bounds__(512) void gate_kernel_old(
    const float* __restrict__ x, const float* __restrict__ w,
    const float* __restrict__ bias, float* __restrict__ out, int n)
{
    __shared__ __align__(16) char smem[65536];
    float  (*w2)[OBK][NE] = reinterpret_cast<float(*)[OBK][NE]>(smem);
    double (*x2)[OBK][34] = reinterpret_cast<double(*)[OBK][34]>(smem + 32768);
    double (*sc)[OBM]     = reinterpret_cast<double(*)[OBM]>(smem);
    const int t = threadIdx.x;
    const int row0 = blockIdx.x * OBM;
    const int we = t & 255;
    const int h8 = (t >> 8) * 8;
    const size_t wbase = (size_t)we * DIM + h8;
    const int rx = t >> 2;
    const int kx = (t & 3) * 4;
    int rr = row0 + rx; if (rr > n - 1) rr = n - 1;
    const size_t xbase = (size_t)rr * DIM + kx;
    const int wv = t >> 6, lane = t & 63;
    const int h = wv & 1, rg = wv >> 1, rb = 8 * rg;
    const int e0 = 128 * h + 2 * lane;
    double acc[8][2];
#pragma unroll
    for (int i = 0; i < 8; ++i) { acc[i][0] = 0.0; acc[i][1] = 0.0; }
    float4 wra = *(const float4*)&w[wbase];
    float4 wrb = *(const float4*)&w[wbase + 4];
    float4 xr = make_float4(0.f, 0.f, 0.f, 0.f);
    if (t < 128) xr = *(const float4*)&x[xbase];
    for (int c = 0; c < ONCH; ++c) {
        const int b = c & 1;
        const float* fa = (const float*)&wra;
        const float* fb = (const float*)&wrb;
#pragma unroll
        for (int q = 0; q < 4; ++q) {
            w2[b][h8 + q][we] = fa[q];
            w2[b][h8 + 4 + q][we] = fb[q];
        }
        if (t < 128) {
            const float* fx = (const float*)&xr;
#pragma unroll
            for (int q = 0; q < 4; ++q) x2[b][kx + q][rx] = (double)fx[q];
        }
        const size_t k0 = (size_t)((c + 1 < ONCH) ? c + 1 : c) * OBK;
        wra = *(const float4*)&w[wbase + k0];
        wrb = *(const float4*)&w[wbase + k0 + 4];
        if (t < 128) xr = *(const float4*)&x[xbase + k0];
        __syncthreads();
#pragma unroll
        for (int kk = 0; kk < OBK; ++kk) {
            const float2 wf = *(const float2*)&w2[b][kk][e0];
            const double wd0 = (double)wf.x, wd1 = (double)wf.y;
            const double2 xp0 = *(const double2*)&x2[b][kk][rb];
            const double2 xp1 = *(const double2*)&x2[b][kk][rb + 2];
            const double2 xp2 = *(const double2*)&x2[b][kk][rb + 4];
            const double2 xp3 = *(const double2*)&x2[b][kk][rb + 6];
            const double xv[8] = {xp0.x, xp0.y, xp1.x, xp1.y, xp2.x, xp2.y, xp3.x, xp3.y};
#pragma unroll
            for (int i = 0; i < 8; ++i) {
                acc[i][0] = fma(xv[i], wd0, acc[i][0]);
                acc[i][1] = fma(xv[i], wd1, acc[i][1]);
            }
        }
    }
    __syncthreads();
#pragma unroll
    for (int j = 0; j < 2; ++j)
#pragma unroll
        for (int q = 0; q < 4; ++q) {
            double2 v; v.x = acc[2 * q][j]; v.y = acc[2 * q + 1][j];
            *(double2*)&sc[e0 + j][rb + 2 * q] = v;
        }
    __syncthreads();
    if (t < OBM) {
        const int row = row0 + t;
        if (row < n) {
            double zmax = -1e300;
            for (int e = 0; e < NE; ++e) zmax = fmax(zmax, sc[e][t]);
            double Z = 0.0;
            for (int e = 0; e < NE; ++e) { double p = exp(sc[e][t] - zmax); sc[e][t] = p; Z += p; }
            const double invZ = 1.0 / Z;
            double gs[NG];
            for (int g = 0; g < NG; ++g) {
                double m1 = -1e300, m2 = -1e300;
                for (int i = 0; i < GSZ; ++i) {
                    double v = sc[g * GSZ + i][t] * invZ + (double)bias[g * GSZ + i];
                    if (v > m1) { m2 = m1; m1 = v; } else if (v > m2) m2 = v;
                }
                gs[g] = m1 + m2;
            }
            unsigned keep = 0;
            for (int tt = 0; tt < TOPG; ++tt) {
                double best = -1e300; int bg = 0;
                for (int g = 0; g < NG; ++g)
                    if (!((keep >> g) & 1u) && gs[g] > best) { best = gs[g]; bg = g; }
                keep |= 1u << bg;
            }
            unsigned long long tk[4] = {0ull, 0ull, 0ull, 0ull};
            float* out_w = out;
            float* out_i = out + (size_t)n * TOPK_N;
            for (int pp = 0; pp < TOPK_N; ++pp) {
                double best = -1e300; int be = 0;
                for (int e = 0; e < NE; ++e) {
                    if (!((keep >> (e >> 5)) & 1u)) continue;
                    if ((tk[e >> 6] >> (e & 63)) & 1ull) continue;
                    double s = sc[e][t] * invZ + (double)bias[e];
                    if (s > best) { best = s; be = e; }
                }
                tk[be >> 6] |= 1ull << (be & 63);
                out_w[(size_t)row * TOPK_N + pp] = (float)(sc[be][t] * invZ * 2.5);
                out_i[(size_t)row * TOPK_N + pp] = (float)be;
            }
        }
    }
}

extern "C" void kernel_launch(void* const* d_in, const int* in_sizes, int n_in,
                              void* d_out, int out_size, void* d_ws, size_t ws_size,
                              hipStream_t stream) {
    const float* x  = (const float*)d_in[0];
    const float* w  = (const float*)d_in[1];
    const float* b  = (const float*)d_in[2];
    float* out      = (float*)d_out;
    const int n     = in_sizes[0] / DIM;
    const int np    = (n + BM - 1) & ~(BM - 1);

    const size_t WBYTES   = (size_t)16 * NKT * 64 * 8 * 2;  // 3,670,016 per array
    const size_t off_list = 4096;
    const size_t off_wh   = off_list + (((size_t)np * 4 + 255) & ~(size_t)255);
    const size_t off_wl   = off_wh + WBYTES;
    const size_t off_part = off_wl + WBYTES;
    const size_t need     = off_part + (size_t)KSPLIT * np * NE * 4;

    if (ws_size < need) {
        gate_kernel_old<<<(n + OBM - 1) / OBM, 512, 0, stream>>>(x, w, b, out, n);
        return;
    }
    char* ws = (char*)d_ws;
    unsigned* counter   = (unsigned*)ws;
    int* list           = (int*)(ws + off_list);
    unsigned short* wh  = (unsigned short*)(ws + off_wh);
    unsigned short* wl  = (unsigned short*)(ws + off_wl);
    float* part         = (float*)(ws + off_part);

    hipMemsetAsync(counter, 0, 4, stream);
    k0_repack<<<(16 * NKT * 64) / 256, 256, 0, stream>>>(w, wh, wl);
    k1_gemm<<<(np / BM) * KSPLIT, 512, 0, stream>>>(x, wh, wl, part, n, np);
    k1b_route<<<np / 32, 256, 0, stream>>>(part, b, out, counter, list, n, np, (unsigned)np);
    k2_exact<<<(n + K2_ROWS - 1) / K2_ROWS, 1024, 0, stream>>>(x, w, b, out, counter, list, n, (unsigned)np);
}